// Round 1
// 249.214 us; speedup vs baseline: 1.0349x; 1.0349x over previous
//
#include <hip/hip_runtime.h>
#include <hip/hip_bf16.h>
#include <stdint.h>

// Problem: B=32, N=2048, D=512, K=64, G=16, M=B*N=65536, C=K+G=80
// Inputs fp32; OUTPUT fp32.
typedef __attribute__((ext_vector_type(8))) short short8;
typedef __attribute__((ext_vector_type(4))) float f32x4;

__device__ __forceinline__ float b2f(uint16_t u) {
  union { uint32_t i; float f; } v; v.i = ((uint32_t)u) << 16; return v.f;
}
__device__ __forceinline__ uint16_t f2b(float f) {   // RNE fp32->bf16
  uint32_t u = __float_as_uint(f);
  return (uint16_t)((u + 0x7FFFu + ((u >> 16) & 1u)) >> 16);
}
// pack two fp32 bit-patterns -> bf16x2 (lo in low half) via v_perm
__device__ __forceinline__ uint32_t pk2(uint32_t lo, uint32_t hi) {
  return __builtin_amdgcn_perm(hi + 0x8000u, lo + 0x8000u, 0x07060302u);
}

// ---------------------------------------------------------------------------
// K0: clusters fp32 [512][80] -> bf16 MFMA B-fragments, [chunk][q][lr] order:
// cB[(((kk*5+n)*4+q)*16+lr)*8+i] = clusters[kk*32+q*8+i][n*16+lr]
// ---------------------------------------------------------------------------
__global__ void k0_prep(const float* __restrict__ clusters,
                        uint16_t* __restrict__ cB) {
  int gid = blockIdx.x * 256 + threadIdx.x;
  if (gid < 40960) {
    int i = gid & 7, chunk = gid >> 3;
    int lr = chunk & 15, q = (chunk >> 4) & 3, c5 = chunk >> 6;
    int n = c5 % 5, kk = c5 / 5;
    cB[gid] = f2b(clusters[(kk * 32 + q * 8 + i) * 80 + n * 16 + lr]);
  }
}

// ---------------------------------------------------------------------------
// K1: raw[65536][80] = bf16(x) @ bf16(clusters)  (MFMA 16x16x32)
//     + per-block column sum/sumsq partials (part TRANSPOSED: part[c][blk]).
// Single-phase 80KB B staging -> ZERO barriers inside the 16-step K loop.
// grid 512 x 256; 128 rows/block, 32 rows/wave (m=2).
// ---------------------------------------------------------------------------
__global__ __launch_bounds__(256) void k1_gemm1(
    const float* __restrict__ x, const uint16_t* __restrict__ cB,
    float* __restrict__ raw, float* __restrict__ part) {
  __shared__ __align__(16) uint16_t lB[80 * 512];   // 81,920 B -> 2 blocks/CU
  const int t = threadIdx.x;
  const int w = t >> 6, lane = t & 63, q = lane >> 4, lr = lane & 15;
  const int rbase = blockIdx.x * 128 + w * 32;

  // stage all of cB (linear copy), once
  {
    const uint4* src = (const uint4*)cB;
#pragma unroll 4
    for (int it = 0; it < 20; ++it)
      *(uint4*)&lB[(it * 256 + t) * 8] = src[it * 256 + t];
  }

  f32x4 acc[2][5];
#pragma unroll
  for (int m = 0; m < 2; ++m)
#pragma unroll
    for (int n = 0; n < 5; ++n) acc[m][n] = 0.f;

  const float* xa = x + (size_t)(rbase + lr) * 512 + q * 8;
  __syncthreads();

#pragma unroll 8
  for (int kk = 0; kk < 16; ++kk) {
    short8 a[2], bf[5];
#pragma unroll
    for (int m = 0; m < 2; ++m) {
      uint4 u0 = *(const uint4*)(xa + (size_t)m * 16 * 512 + kk * 32);
      uint4 u1 = *(const uint4*)(xa + (size_t)m * 16 * 512 + kk * 32 + 4);
      union { short8 s; uint32_t u[4]; } av;
      av.u[0] = pk2(u0.x, u0.y); av.u[1] = pk2(u0.z, u0.w);
      av.u[2] = pk2(u1.x, u1.y); av.u[3] = pk2(u1.z, u1.w);
      a[m] = av.s;
    }
#pragma unroll
    for (int n = 0; n < 5; ++n)
      bf[n] = *(const short8*)&lB[(((kk * 5 + n) * 4 + q) * 16 + lr) * 8];
#pragma unroll
    for (int m = 0; m < 2; ++m)
#pragma unroll
      for (int n = 0; n < 5; ++n)
        acc[m][n] = __builtin_amdgcn_mfma_f32_16x16x32_bf16(a[m], bf[n], acc[m][n], 0, 0, 0);
  }
  __syncthreads();

  float sums[5], sqs[5];
#pragma unroll
  for (int n = 0; n < 5; ++n) {
    float s = 0.f, qq = 0.f;
#pragma unroll
    for (int m = 0; m < 2; ++m) {
#pragma unroll
      for (int r = 0; r < 4; ++r) {
        float v = acc[m][n][r];
        s += v; qq += v * v;
        raw[(size_t)(rbase + m * 16 + q * 4 + r) * 80 + n * 16 + lr] = v;
      }
    }
    s += __shfl_xor(s, 16);  s += __shfl_xor(s, 32);
    qq += __shfl_xor(qq, 16); qq += __shfl_xor(qq, 32);
    sums[n] = s; sqs[n] = qq;
  }

  float* sf = (float*)lB;
  if (lane < 16) {
#pragma unroll
    for (int n = 0; n < 5; ++n) {
      sf[w * 160 + n * 16 + lr] = sums[n];
      sf[640 + w * 160 + n * 16 + lr] = sqs[n];
    }
  }
  __syncthreads();
  if (t < 160) {
    float a0 = sf[t] + sf[160 + t] + sf[320 + t] + sf[480 + t];
    float b0 = sf[640 + t] + sf[800 + t] + sf[960 + t] + sf[1120 + t];
    part[(size_t)t * 512 + blockIdx.x] = a0;            // transposed layout
    part[(size_t)(160 + t) * 512 + blockIdx.x] = b0;
  }
}

// ---------------------------------------------------------------------------
// K2: BN stats -> scale[80] | shift[80]. grid 80 x 64. Coalesced reads.
// ---------------------------------------------------------------------------
__global__ __launch_bounds__(64) void k2_stats(
    const float* __restrict__ part, const float* __restrict__ gamma,
    const float* __restrict__ beta, float* __restrict__ scsh) {
  int c = blockIdx.x, t = threadIdx.x;
  const float* p1 = part + (size_t)c * 512;
  const float* p2 = part + (size_t)(160 + c) * 512;
  float s1 = 0.f, s2 = 0.f;
#pragma unroll
  for (int p = 0; p < 512; p += 64) { s1 += p1[p + t]; s2 += p2[p + t]; }
#pragma unroll
  for (int o = 1; o < 64; o <<= 1) { s1 += __shfl_xor(s1, o); s2 += __shfl_xor(s2, o); }
  if (t == 0) {
    float mean = s1 * (1.f / 65536.f);
    float var = s2 * (1.f / 65536.f) - mean * mean;
    float sc = rsqrtf(var + 1e-5f) * gamma[c];
    scsh[c] = sc;
    scsh[80 + c] = beta[c] - mean * sc;
  }
}

// ---------------------------------------------------------------------------
// k34: fused BN + softmax + GEMM2 (replaces old K3 + K4, no pT round-trip).
// grid 512 = b(32) x s(8 n-slices of 256) x dh(2 d-halves of 256); 256 thr.
// Per 32-n chunk: prefetch x cols + raw rows (T14 split, 1.5 chunks ahead),
// stage x->bf16 LDS [d][n] (octet-swizzled), softmax(80)->p bf16 straight
// into the MFMA B layout, then 16 MFMA/wave per phase. 2 barriers/chunk.
// vpart[s][b][d][k] partials; apart[b][s][k] = per-slice sum of p (bf16-
// consistent with the GEMM operand).
// ---------------------------------------------------------------------------
__global__ __launch_bounds__(256, 2) void k34_fused(
    const float* __restrict__ x, const float* __restrict__ raw_,
    const float* __restrict__ scsh, float* __restrict__ vpart,
    float* __restrict__ apart) {
  __shared__ __align__(16) uint16_t sx[2][256 * 40];  // 40,960 B  [d][n] bf16
  __shared__ __align__(16) uint16_t sp[2][64 * 40];   // 10,240 B  [k][n] bf16
  __shared__ float sc[80], sh[80];
  __shared__ float ared[4 * 64];

  const int t = threadIdx.x;
  const int b = blockIdx.x >> 4;
  const int s = (blockIdx.x >> 1) & 7;
  const int dh = blockIdx.x & 1;
  const int w = t >> 6, lane = t & 63, q = lane >> 4, lr = lane & 15;

  const int dd = t;                                   // staged d column 0..255
  const int sg = ((dd >> 2) + (dd >> 4)) & 3;         // write octet swizzle
  const int r_ = t >> 3, cg = t & 7;                  // softmax: row, 10-col grp
  const int kk_ = t & 63, ng = t >> 6;                // a_sum: k, n-octet group

  if (t < 80) sc[t] = scsh[t];
  else if (t < 160) sh[t - 80] = scsh[t];

  const float* xb = x + ((size_t)b * 2048 + (size_t)s * 256) * 512 + dh * 256;
  const float* rawb = raw_ + ((size_t)b * 2048 + (size_t)s * 256) * 80;

  f32x4 acc[4][4];
#pragma unroll
  for (int m = 0; m < 4; ++m)
#pragma unroll
    for (int j = 0; j < 4; ++j) acc[m][j] = 0.f;

  float xf[32], yf[10];
  float asum = 0.f;

#define XLOAD(c)                                                          \
  {                                                                       \
    const float* xc = xb + (size_t)(c) * 32 * 512 + dd;                   \
    _Pragma("unroll")                                                     \
    for (int j = 0; j < 32; ++j) xf[j] = xc[(size_t)j * 512];             \
  }
#define RLOAD(c)                                                          \
  {                                                                       \
    const float* rc = rawb + (size_t)((c) * 32 + r_) * 80 + cg * 10;      \
    _Pragma("unroll")                                                     \
    for (int j = 0; j < 5; ++j) {                                         \
      float2 v2 = *(const float2*)(rc + j * 2);                           \
      yf[2 * j] = v2.x; yf[2 * j + 1] = v2.y;                             \
    }                                                                     \
  }
#define XSTORE(buf)                                                       \
  {                                                                       \
    _Pragma("unroll")                                                     \
    for (int g = 0; g < 4; ++g) {                                         \
      union { uint4 u; uint32_t w4[4]; } pv;                              \
      _Pragma("unroll")                                                   \
      for (int h = 0; h < 4; ++h)                                         \
        pv.w4[h] = pk2(__float_as_uint(xf[g * 8 + h * 2]),                \
                       __float_as_uint(xf[g * 8 + h * 2 + 1]));           \
      *(uint4*)&sx[buf][dd * 40 + ((g ^ sg) << 3)] = pv.u;                \
    }                                                                     \
  }
#define SOFTMAX(buf)                                                      \
  {                                                                       \
    float yy[10]; float mx = -3.0e38f;                                    \
    _Pragma("unroll")                                                     \
    for (int j = 0; j < 10; ++j) {                                        \
      int cc = cg * 10 + j;                                               \
      yy[j] = yf[j] * sc[cc] + sh[cc];                                    \
      mx = fmaxf(mx, yy[j]);                                              \
    }                                                                     \
    mx = fmaxf(mx, __shfl_xor(mx, 1));                                    \
    mx = fmaxf(mx, __shfl_xor(mx, 2));                                    \
    mx = fmaxf(mx, __shfl_xor(mx, 4));                                    \
    float sum = 0.f;                                                      \
    _Pragma("unroll")                                                     \
    for (int j = 0; j < 10; ++j) { yy[j] = __expf(yy[j] - mx); sum += yy[j]; } \
    sum += __shfl_xor(sum, 1);                                            \
    sum += __shfl_xor(sum, 2);                                            \
    sum += __shfl_xor(sum, 4);                                            \
    float inv = 1.0f / sum;                                               \
    _Pragma("unroll")                                                     \
    for (int j = 0; j < 10; ++j) {                                        \
      int cc = cg * 10 + j;                                               \
      if (cc < 64) sp[buf][cc * 40 + r_] = f2b(yy[j] * inv);              \
    }                                                                     \
  }
#define GEMM(buf)                                                         \
  {                                                                       \
    const uint16_t* sxc = sx[buf];                                        \
    const uint16_t* spc = sp[buf];                                        \
    short8 bfr[4];                                                        \
    _Pragma("unroll")                                                     \
    for (int j = 0; j < 4; ++j)                                           \
      bfr[j] = *(const short8*)&spc[(j * 16 + lr) * 40 + (q << 3)];       \
    _Pragma("unroll")                                                     \
    for (int m = 0; m < 4; ++m) {                                         \
      int row = w * 64 + m * 16 + lr;                                     \
      int swr = ((row >> 2) + (row >> 4)) & 3;                            \
      short8 af = *(const short8*)&sxc[row * 40 + ((q ^ swr) << 3)];      \
      _Pragma("unroll")                                                   \
      for (int j = 0; j < 4; ++j)                                         \
        acc[m][j] = __builtin_amdgcn_mfma_f32_16x16x32_bf16(af, bfr[j], acc[m][j], 0, 0, 0); \
    }                                                                     \
    union { uint4 u; uint16_t us[8]; } pv;                                \
    pv.u = *(const uint4*)&spc[kk_ * 40 + (ng << 3)];                     \
    _Pragma("unroll")                                                     \
    for (int i = 0; i < 8; ++i) asum += b2f(pv.us[i]);                    \
  }

  XLOAD(0) RLOAD(0)
  __syncthreads();                 // sc/sh visible
  XSTORE(0) SOFTMAX(0)
  XLOAD(1) RLOAD(1)
  __syncthreads();                 // buf0 published

  for (int c = 0; c < 8; ++c) {
    const int cur = c & 1;
    GEMM(cur)
    __syncthreads();               // all reads of buf cur done
    if (c < 7) {
      XSTORE(cur ^ 1) SOFTMAX(cur ^ 1)   // stage chunk c+1 from prefetch regs
      if (c < 6) { XLOAD(c + 2) RLOAD(c + 2) }
      __syncthreads();             // buf cur^1 published
    }
  }
#undef XLOAD
#undef RLOAD
#undef XSTORE
#undef SOFTMAX
#undef GEMM

  ared[ng * 64 + kk_] = asum;
  __syncthreads();
  if (dh == 0 && t < 64) {
    float a = ared[t] + ared[64 + t] + ared[128 + t] + ared[192 + t];
    apart[((size_t)b * 8 + s) * 64 + t] = a;
  }

  float* vp = vpart + ((size_t)s * 32 + b) * 32768;
#pragma unroll
  for (int m = 0; m < 4; ++m)
#pragma unroll
    for (int j = 0; j < 4; ++j)
#pragma unroll
      for (int r2 = 0; r2 < 4; ++r2)
        vp[(size_t)(dh * 256 + w * 64 + m * 16 + q * 4 + r2) * 64 + j * 16 + lr] =
            acc[m][j][r2];
}

// ---------------------------------------------------------------------------
// K5a: v = sum_s vpart[s] - a_sum*c2 ; write vfull + partial column sumsq.
// grid 512 (32 b x 16 dg) x 256.
// ---------------------------------------------------------------------------
__global__ __launch_bounds__(256) void k5a_red(
    const float* __restrict__ vpart, const float* __restrict__ apart,
    const float* __restrict__ c2, float* __restrict__ vfull,
    float* __restrict__ csq) {
  __shared__ float las[64];
  __shared__ float sred[256];
  const int t = threadIdx.x, b = blockIdx.x >> 4, dg = blockIdx.x & 15;
  if (t < 64) {
    float a = 0.f;
#pragma unroll
    for (int s = 0; s < 8; ++s) a += apart[((size_t)b * 8 + s) * 64 + t];
    las[t] = a;
  }
  __syncthreads();
  const int k = t & 63, di = t >> 6;
  float ssq = 0.f;
#pragma unroll
  for (int jj = 0; jj < 8; ++jj) {
    int d = dg * 32 + di * 8 + jj;
    size_t i = (size_t)d * 64 + k;
    float v = -las[k] * c2[i];
#pragma unroll
    for (int s = 0; s < 8; ++s) v += vpart[((size_t)s * 32 + b) * 32768 + i];
    vfull[(size_t)b * 32768 + i] = v;
    ssq += v * v;
  }
  sred[di * 64 + k] = ssq;
  __syncthreads();
  if (t < 64) {
    csq[(size_t)blockIdx.x * 64 + t] =
        sred[t] + sred[64 + t] + sred[128 + t] + sred[192 + t];
  }
}

// ---------------------------------------------------------------------------
// K5b: linv[b][k], gscl[b]. grid 32 x 64.
// ---------------------------------------------------------------------------
__global__ __launch_bounds__(64) void k5b_fin(
    const float* __restrict__ csq, float* __restrict__ linv,
    float* __restrict__ gscl) {
  const int t = threadIdx.x, b = blockIdx.x;
  float ssq = 0.f;
#pragma unroll
  for (int dg = 0; dg < 16; ++dg) ssq += csq[(size_t)(b * 16 + dg) * 64 + t];
  float iv = 1.0f / fmaxf(sqrtf(ssq), 1e-12f);
  linv[b * 64 + t] = iv;
  float contrib = ssq * iv * iv;
#pragma unroll
  for (int o = 1; o < 64; o <<= 1) contrib += __shfl_xor(contrib, o);
  if (t == 0) gscl[b] = 1.0f / fmaxf(sqrtf(contrib), 1e-12f);
}

// ---------------------------------------------------------------------------
// K5c: out = vfull * linv[k] * gscl[b]. grid 512 (32b x 16seg) x 256.
// ---------------------------------------------------------------------------
__global__ __launch_bounds__(256) void k5c_norm(
    const float* __restrict__ vfull, const float* __restrict__ linv,
    const float* __restrict__ gscl, float* __restrict__ out) {
  __shared__ float lv[64];
  __shared__ float gs;
  const int t = threadIdx.x, b = blockIdx.x >> 4, seg = blockIdx.x & 15;
  if (t < 64) lv[t] = linv[b * 64 + t];
  if (t == 64) gs = gscl[b];
  __syncthreads();
  const float gg = gs;
#pragma unroll
  for (int u = 0; u < 2; ++u) {
    int i = seg * 2048 + u * 1024 + t * 4;
    int k0 = i & 63;
    float4 a = *(const float4*)(vfull + (size_t)b * 32768 + i);
    float4 o;
    o.x = a.x * lv[k0 + 0] * gg;
    o.y = a.y * lv[k0 + 1] * gg;
    o.z = a.z * lv[k0 + 2] * gg;
    o.w = a.w * lv[k0 + 3] * gg;
    *(float4*)&out[(size_t)b * 32768 + i] = o;
  }
}

// ---------------------------------------------------------------------------
// Workspace (bytes), total 59,663,104:
//   cB    @ 0        : 81,920
//   part  @ 81920    : 320*512*4    =   655,360
//   scsh  @ 737280   : 640
//   raw   @ 737920   : 65536*80*4   = 20,971,520
//   vpart @ 21709440 : 8*32*32768*4 = 33,554,432
//   vfull @ 55263872 : 32*32768*4   =  4,194,304
//   apart @ 59458176 : 32*8*64*4    =     65,536
//   csq   @ 59523712 : 512*64*4     =    131,072
//   linv  @ 59654784 : 2048*4       =      8,192
//   gscl  @ 59662976 : 32*4         =        128
// ---------------------------------------------------------------------------
extern "C" void kernel_launch(void* const* d_in, const int* in_sizes, int n_in,
                              void* d_out, int out_size, void* d_ws, size_t ws_size,
                              hipStream_t stream) {
  const float* x         = (const float*)d_in[0];
  const float* clusters  = (const float*)d_in[1];
  const float* clusters2 = (const float*)d_in[2];
  const float* gamma     = (const float*)d_in[3];
  const float* beta      = (const float*)d_in[4];
  float* out = (float*)d_out;
  char* ws = (char*)d_ws;

  uint16_t* cB = (uint16_t*)(ws + 0);
  float* part  = (float*)(ws + 81920);
  float* scsh  = (float*)(ws + 737280);
  float* raw   = (float*)(ws + 737920);
  float* vpart = (float*)(ws + 21709440);
  float* vfull = (float*)(ws + 55263872);
  float* apart = (float*)(ws + 59458176);
  float* csq   = (float*)(ws + 59523712);
  float* linv  = (float*)(ws + 59654784);
  float* gscl  = (float*)(ws + 59662976);

  hipLaunchKernelGGL(k0_prep,   dim3(160), dim3(256), 0, stream, clusters, cB);
  hipLaunchKernelGGL(k1_gemm1,  dim3(512), dim3(256), 0, stream, x, cB, raw, part);
  hipLaunchKernelGGL(k2_stats,  dim3(80),  dim3(64),  0, stream, part, gamma, beta, scsh);
  hipLaunchKernelGGL(k34_fused, dim3(512), dim3(256), 0, stream, x, raw, scsh, vpart, apart);
  hipLaunchKernelGGL(k5a_red,   dim3(512), dim3(256), 0, stream, vpart, apart, clusters2, vfull, csq);
  hipLaunchKernelGGL(k5b_fin,   dim3(32),  dim3(64),  0, stream, csq, linv, gscl);
  hipLaunchKernelGGL(k5c_norm,  dim3(512), dim3(256), 0, stream, vfull, linv, gscl, out);
}